// Round 20
// baseline (152.205 us; speedup 1.0000x reference)
//
#include <hip/hip_runtime.h>

#define NN 100000
#define IC 128
#define HD 64
#define NEG 0.2f
#define NPB 32                       // dst-nodes per bucket
#define NBKT (NN / NPB)              // 3125 buckets
#define CAP 768                      // max edges per bucket in k_pg (avg ~544)
#define TILE 8192                    // edges per k_part block -> 208 blocks
#define NIT 16                       // TILE / 512 threads
#define LSTRIDE (NBKT + 11)          // 3136, lofs row stride

typedef float f32x4 __attribute__((ext_vector_type(4)));
typedef short s16x8 __attribute__((ext_vector_type(8)));

__device__ __forceinline__ unsigned short f32_to_bf16u(float f) {
  union { float f; unsigned int i; } v;
  v.f = f;
  unsigned int b = v.i;
  b += 0x7FFFu + ((b >> 16) & 1u);   // round-to-nearest-even
  return (unsigned short)(b >> 16);
}

// h(bf16) = x @ W via MFMA; fused a_src/a_dst. (No global state to zero.)
__global__ __launch_bounds__(256) void k_gemm(const float* __restrict__ x,
                                              const float* __restrict__ W,
                                              const float* __restrict__ att_s,
                                              const float* __restrict__ att_d,
                                              unsigned short* __restrict__ hb,
                                              float* __restrict__ as_,
                                              float* __restrict__ ad_) {
  __shared__ unsigned short xb[64 * 128];   // [node][k] bf16, swizzled
  __shared__ unsigned short wt[64 * 128];   // [col][k] = W^T bf16, swizzled
  const int tid = threadIdx.x;
  const int n0 = blockIdx.x * 64;

  #pragma unroll
  for (int i = 0; i < 8; ++i) {
    int f = i * 256 + tid;
    int r = f >> 5, k0 = (f & 31) << 2;
    float4 v = make_float4(0.f, 0.f, 0.f, 0.f);
    if (n0 + r < NN) v = *(const float4*)&x[(size_t)(n0 + r) * IC + k0];
    ushort4 u;
    u.x = f32_to_bf16u(v.x); u.y = f32_to_bf16u(v.y);
    u.z = f32_to_bf16u(v.z); u.w = f32_to_bf16u(v.w);
    int idx = r * 128 + k0;
    *(ushort4*)&xb[idx ^ ((r & 7) << 3)] = u;
  }
  #pragma unroll
  for (int i = 0; i < 8; ++i) {
    int f = i * 256 + tid;
    int k = f >> 4, c0 = (f & 15) << 2;
    float4 v = *(const float4*)&W[k * HD + c0];
    const float* vf = (const float*)&v;
    #pragma unroll
    for (int j = 0; j < 4; ++j) {
      int c = c0 + j;
      int idx = c * 128 + k;
      wt[idx ^ ((c & 7) << 3)] = f32_to_bf16u(vf[j]);
    }
  }
  __syncthreads();

  const int wv = tid >> 6, lane = tid & 63;
  const int fr = lane & 15;
  const int fq = lane >> 4;
  const int nodeR = wv * 16 + fr;
  f32x4 acc[4] = {};
  #pragma unroll
  for (int kb = 0; kb < 4; ++kb) {
    int ks = kb * 32 + fq * 8;
    int ia = nodeR * 128 + ks;
    s16x8 af = *(s16x8*)&xb[ia ^ ((nodeR & 7) << 3)];
    #pragma unroll
    for (int cg = 0; cg < 4; ++cg) {
      int col = cg * 16 + fr;
      int ib = col * 128 + ks;
      s16x8 bfr = *(s16x8*)&wt[ib ^ ((col & 7) << 3)];
      acc[cg] = __builtin_amdgcn_mfma_f32_16x16x32_bf16(af, bfr, acc[cg], 0, 0, 0);
    }
  }

  float atts[4], attd[4];
  #pragma unroll
  for (int cg = 0; cg < 4; ++cg) {
    atts[cg] = att_s[cg * 16 + fr];
    attd[cg] = att_d[cg * 16 + fr];
  }
  __syncthreads();
  unsigned short* ho = xb;

  #pragma unroll
  for (int j = 0; j < 4; ++j) {
    int nrel = wv * 16 + fq * 4 + j;
    float ps = acc[0][j]*atts[0] + acc[1][j]*atts[1]
             + acc[2][j]*atts[2] + acc[3][j]*atts[3];
    float pd = acc[0][j]*attd[0] + acc[1][j]*attd[1]
             + acc[2][j]*attd[2] + acc[3][j]*attd[3];
    #pragma unroll
    for (int mk = 1; mk < 16; mk <<= 1) {
      ps += __shfl_xor(ps, mk);
      pd += __shfl_xor(pd, mk);
    }
    if (fr == 0 && n0 + nrel < NN) { as_[n0 + nrel] = ps; ad_[n0 + nrel] = pd; }
    #pragma unroll
    for (int cg = 0; cg < 4; ++cg)
      ho[nrel * 72 + cg * 16 + fr] = f32_to_bf16u(acc[cg][j]);
  }
  __syncthreads();

  {
    int node = tid >> 2, ch = (tid & 3) << 4;
    if (n0 + node < NN) {
      ushort4 a0 = *(ushort4*)&ho[node * 72 + ch];
      ushort4 a1 = *(ushort4*)&ho[node * 72 + ch + 4];
      ushort4 a2 = *(ushort4*)&ho[node * 72 + ch + 8];
      ushort4 a3 = *(ushort4*)&ho[node * 72 + ch + 12];
      unsigned short* dst = &hb[(size_t)(n0 + node) * HD + ch];
      *(ushort4*)(dst) = a0;
      *(ushort4*)(dst + 4) = a1;
      *(ushort4*)(dst + 8) = a2;
      *(ushort4*)(dst + 12) = a3;
    }
  }
}

// Block-local counting sort: rank in LDS, scan 3125 counters in LDS, write
// the sorted tile to the block's OWN contiguous 64 KB region (full-line
// evictions, zero global atomics). Also writes prefix row lofs[blk][*] and
// p_lin (both coalesced). Payload: int2{(src<<5)|node, bits(p)}.
__global__ __launch_bounds__(512) void k_part(const int* __restrict__ ei,
                                              const float* __restrict__ as_,
                                              const float* __restrict__ ad_,
                                              int2* __restrict__ sorted,
                                              int* __restrict__ lofs,
                                              float* __restrict__ p_lin,
                                              int E, int M) {
  __shared__ int lcnt[NBKT];
  __shared__ int wpart[8];
  const int tid = threadIdx.x;
  const int blk = blockIdx.x;
  const int base = blk * TILE;

  for (int c = tid; c < NBKT; c += 512) lcnt[c] = 0;
  __syncthreads();

  int pkx[NIT], rb[NIT];
  float tv[NIT];
  #pragma unroll
  for (int i = 0; i < NIT; ++i) {
    int m = base + i * 512 + tid;
    if (m < M) {
      int s, d;
      if (m < E) { s = ei[m]; d = ei[E + m]; }
      else       { s = m - E; d = s; }
      int b = d >> 5;
      pkx[i] = (s << 5) | (d & 31);
      tv[i] = as_[s] + ad_[d];
      int r = atomicAdd(&lcnt[b], 1);        // r < 8192 -> 13 bits
      rb[i] = (b << 13) | r;                 // b < 3125 -> 12 bits
    } else rb[i] = -1;
  }
  __syncthreads();

  // in-place exclusive scan of lcnt[0..NBKT): 7 elements per thread
  {
    int a[7];
    int base7 = tid * 7, lsum = 0;
    #pragma unroll
    for (int j = 0; j < 7; ++j) {
      int idx = base7 + j;
      a[j] = (idx < NBKT) ? lcnt[idx] : 0;
      lsum += a[j];
    }
    int v = lsum;
    #pragma unroll
    for (int off = 1; off < 64; off <<= 1) {
      int nv = __shfl_up(v, off);
      if ((tid & 63) >= off) v += nv;
    }
    if ((tid & 63) == 63) wpart[tid >> 6] = v;
    __syncthreads();
    int woff = 0;
    for (int w0 = 0; w0 < (tid >> 6); ++w0) woff += wpart[w0];
    int start = woff + v - lsum;             // exclusive prefix for this thread
    #pragma unroll
    for (int j = 0; j < 7; ++j) {
      int idx = base7 + j;
      if (idx < NBKT) { lcnt[idx] = start; start += a[j]; }
    }
  }
  __syncthreads();

  // write prefix row (coalesced) + total
  {
    int* row = lofs + (size_t)blk * LSTRIDE;
    for (int c = tid; c < NBKT; c += 512) row[c] = lcnt[c];
    if (tid == 0) {
      int tot = min(M - base, TILE);
      row[NBKT] = tot;
    }
  }

  // write sorted tile into own region (scattered 8B within 64 KB -> L2)
  #pragma unroll
  for (int i = 0; i < NIT; ++i) {
    if (rb[i] >= 0) {
      int m = base + i * 512 + tid;
      float t = tv[i];
      t = t > 0.f ? t : NEG * t;
      float p = __expf(t);
      p_lin[m] = p;
      int b = (unsigned)rb[i] >> 13, r = rb[i] & 8191;
      sorted[(size_t)blk * TILE + lcnt[b] + r] =
          make_int2(pkx[i], __float_as_int(p));
    }
  }
}

// One block per bucket of 32 nodes. Stage via deterministic sub-runs
// (thread t owns part-block t's run): pass1 counts nodes, pass2 places into
// sp. Then the proven dword channel-pair gather (2 edges per VMEM inst).
__global__ __launch_bounds__(256) void k_pg(const int* __restrict__ lofs,
                                            const int2* __restrict__ sorted,
                                            const unsigned short* __restrict__ hb,
                                            const float* __restrict__ bias,
                                            float* __restrict__ out,
                                            float* __restrict__ denom,
                                            int npart) {
  __shared__ int2 sp[CAP];
  __shared__ int cnt2[NPB], nstart[NPB], cur[NPB];
  __shared__ float dls[NPB];
  const int b = blockIdx.x;
  const int d0 = b << 5;
  const int tid = threadIdx.x;
  const char* hbb = (const char*)hb;

  if (tid < NPB) cnt2[tid] = 0;
  __syncthreads();

  // pass 1: count nodes across this bucket's sub-runs
  for (int t = tid; t < npart; t += 256) {
    const int* row = lofs + (size_t)t * LSTRIDE;
    int st = row[b], en = row[b + 1];
    const int2* src = sorted + (size_t)t * TILE;
    for (int e = st; e < en; ++e) atomicAdd(&cnt2[src[e].x & 31], 1);
  }
  __syncthreads();

  if (tid < 32) {
    int a = cnt2[tid];
    int va = a;
    #pragma unroll
    for (int off = 1; off < 32; off <<= 1) {
      int na = __shfl_up(va, off);
      if (tid >= off) va += na;
    }
    nstart[tid] = va - a;
    cur[tid] = va - a;
  }
  __syncthreads();

  // pass 2: place {src*128, p} into sp, node-segmented
  for (int t = tid; t < npart; t += 256) {
    const int* row = lofs + (size_t)t * LSTRIDE;
    int st = row[b], en = row[b + 1];
    const int2* src = sorted + (size_t)t * TILE;
    for (int e = st; e < en; ++e) {
      int2 v = src[e];
      int slot = atomicAdd(&cur[v.x & 31], 1);
      if (slot < CAP) sp[slot] = make_int2((v.x & ~31) << 2, v.y);
    }
  }
  __syncthreads();

  const int wv = tid >> 6, lane = tid & 63;
  const int half = lane >> 5;          // which edge of a pair
  const int hl = lane & 31;            // channel-pair index
  const unsigned chb = (unsigned)hl << 2;
  const float2 bs2 = *(const float2*)&bias[2 * hl];

  for (int n = wv; n < NPB; n += 4) {
    int beg = nstart[n], end = min(beg + cnt2[n], CAP);
    float ax = 0.f, ay = 0.f, dens = 0.f;
    int e = beg;
    for (; e + 8 <= end; e += 8) {        // 8 edges per iter, 4 loads in flight
      #pragma unroll
      for (int j = 0; j < 4; ++j) {
        int2 v = sp[e + 2 * j + half];
        unsigned u = *(const unsigned*)(hbb + ((unsigned)v.x + chb));
        float p = __int_as_float(v.y);
        dens += p;
        ax += p * __uint_as_float(u << 16);
        ay += p * __uint_as_float(u & 0xffff0000u);
      }
    }
    {                                      // guarded epilogue: 0-7 edges
      #pragma unroll
      for (int j = 0; j < 4; ++j) {
        int idx = e + 2 * j + half;
        if (idx < end) {
          int2 v = sp[idx];
          unsigned u = *(const unsigned*)(hbb + ((unsigned)v.x + chb));
          float p = __int_as_float(v.y);
          dens += p;
          ax += p * __uint_as_float(u << 16);
          ay += p * __uint_as_float(u & 0xffff0000u);
        }
      }
    }
    ax += __shfl_xor(ax, 32);
    ay += __shfl_xor(ay, 32);
    dens += __shfl_xor(dens, 32);
    if (half == 0) {
      float rd = 1.f / (dens + 1e-16f);
      float2 o;
      o.x = ax * rd + bs2.x;
      o.y = ay * rd + bs2.y;
      *(float2*)&out[(size_t)(d0 + n) * HD + 2 * hl] = o;
      if (hl == 0) dls[n] = dens;
    }
  }
  __syncthreads();
  if (tid < NPB) denom[d0 + tid] = dls[tid];  // coalesced (NN % NPB == 0)
}

// alpha_out[m] = p_lin[m] / denom[dst]
__global__ __launch_bounds__(256) void k_alpha(const int* __restrict__ ei,
                                               const float* __restrict__ p_lin,
                                               const float* __restrict__ denom,
                                               float* __restrict__ alpha_out,
                                               int E, int M) {
  int m = blockIdx.x * 256 + threadIdx.x;
  if (m >= M) return;
  int d = (m < E) ? ei[E + m] : (m - E);
  alpha_out[m] = p_lin[m] / (denom[d] + 1e-16f);
}

extern "C" void kernel_launch(void* const* d_in, const int* in_sizes, int n_in,
                              void* d_out, int out_size, void* d_ws, size_t ws_size,
                              hipStream_t stream) {
  const float* x     = (const float*)d_in[0];
  const int*   ei    = (const int*)d_in[1];   // [2, E]: src row then dst row
  const float* W     = (const float*)d_in[2];
  const float* att_s = (const float*)d_in[3];
  const float* att_d = (const float*)d_in[4];
  const float* bias  = (const float*)d_in[5];

  const int E = in_sizes[1] / 2;
  const int M = E + NN;
  const int npart = (M + TILE - 1) / TILE;    // 208

  float* out       = (float*)d_out;              // [NN*HD]
  float* alpha_out = out + (size_t)NN * HD;      // [M]

  char* w = (char*)d_ws;
  auto alloc = [&](size_t bytes) {
    char* p = w;
    w += (bytes + 15) & ~(size_t)15;
    return p;
  };
  unsigned short* hb = (unsigned short*)alloc(sizeof(unsigned short) * (size_t)NN * HD);
  float* as_    = (float*)alloc(sizeof(float) * NN);
  float* ad_    = (float*)alloc(sizeof(float) * NN);
  float* denom  = (float*)alloc(sizeof(float) * NN);
  float* p_lin  = (float*)alloc(sizeof(float) * (size_t)M);
  int*   lofs   = (int*)alloc(sizeof(int) * (size_t)npart * LSTRIDE);
  int2*  sorted = (int2*)alloc(sizeof(int2) * (size_t)npart * TILE);

  k_gemm<<<(NN + 63) / 64, 256, 0, stream>>>(x, W, att_s, att_d, hb, as_, ad_);
  k_part<<<npart, 512, 0, stream>>>(ei, as_, ad_, sorted, lofs, p_lin, E, M);
  k_pg<<<NBKT, 256, 0, stream>>>(lofs, sorted, hb, bias, out, denom, npart);
  k_alpha<<<(M + 255) / 256, 256, 0, stream>>>(ei, p_lin, denom, alpha_out,
                                               E, M);
}

// Round 21
// 105.742 us; speedup vs baseline: 1.4394x; 1.4394x over previous
//
#include <hip/hip_runtime.h>

#define NN 100000
#define IC 128
#define HD 64
#define NEG 0.2f
#define NPB 64                       // dst-nodes per bucket
#define NBKT ((NN + NPB - 1) / NPB)  // 1563 buckets (last has 32 nodes)
#define CAP 1536                     // edges capacity per bucket (avg ~1088, +13s)
#define TILE 4096                    // edges per k_part block -> 416 blocks
#define NIT 8                        // TILE / 512 threads

typedef float f32x4 __attribute__((ext_vector_type(4)));
typedef short s16x8 __attribute__((ext_vector_type(8)));

__device__ __forceinline__ unsigned short f32_to_bf16u(float f) {
  union { float f; unsigned int i; } v;
  v.f = f;
  unsigned int b = v.i;
  b += 0x7FFFu + ((b >> 16) & 1u);   // round-to-nearest-even
  return (unsigned short)(b >> 16);
}

// h(bf16) = x @ W via MFMA; fused a_src/a_dst; zeroes bktcur (grid == NBKT).
__global__ __launch_bounds__(256) void k_gemm(const float* __restrict__ x,
                                              const float* __restrict__ W,
                                              const float* __restrict__ att_s,
                                              const float* __restrict__ att_d,
                                              unsigned short* __restrict__ hb,
                                              float* __restrict__ as_,
                                              float* __restrict__ ad_,
                                              int* __restrict__ bktcur) {
  __shared__ unsigned short xb[64 * 128];   // [node][k] bf16, swizzled
  __shared__ unsigned short wt[64 * 128];   // [col][k] = W^T bf16, swizzled
  const int tid = threadIdx.x;
  const int n0 = blockIdx.x * 64;
  if (tid == 0 && blockIdx.x < NBKT) bktcur[blockIdx.x] = 0;

  #pragma unroll
  for (int i = 0; i < 8; ++i) {
    int f = i * 256 + tid;
    int r = f >> 5, k0 = (f & 31) << 2;
    float4 v = make_float4(0.f, 0.f, 0.f, 0.f);
    if (n0 + r < NN) v = *(const float4*)&x[(size_t)(n0 + r) * IC + k0];
    ushort4 u;
    u.x = f32_to_bf16u(v.x); u.y = f32_to_bf16u(v.y);
    u.z = f32_to_bf16u(v.z); u.w = f32_to_bf16u(v.w);
    int idx = r * 128 + k0;
    *(ushort4*)&xb[idx ^ ((r & 7) << 3)] = u;
  }
  #pragma unroll
  for (int i = 0; i < 8; ++i) {
    int f = i * 256 + tid;
    int k = f >> 4, c0 = (f & 15) << 2;
    float4 v = *(const float4*)&W[k * HD + c0];
    const float* vf = (const float*)&v;
    #pragma unroll
    for (int j = 0; j < 4; ++j) {
      int c = c0 + j;
      int idx = c * 128 + k;
      wt[idx ^ ((c & 7) << 3)] = f32_to_bf16u(vf[j]);
    }
  }
  __syncthreads();

  const int wv = tid >> 6, lane = tid & 63;
  const int fr = lane & 15;
  const int fq = lane >> 4;
  const int nodeR = wv * 16 + fr;
  f32x4 acc[4] = {};
  #pragma unroll
  for (int kb = 0; kb < 4; ++kb) {
    int ks = kb * 32 + fq * 8;
    int ia = nodeR * 128 + ks;
    s16x8 af = *(s16x8*)&xb[ia ^ ((nodeR & 7) << 3)];
    #pragma unroll
    for (int cg = 0; cg < 4; ++cg) {
      int col = cg * 16 + fr;
      int ib = col * 128 + ks;
      s16x8 bfr = *(s16x8*)&wt[ib ^ ((col & 7) << 3)];
      acc[cg] = __builtin_amdgcn_mfma_f32_16x16x32_bf16(af, bfr, acc[cg], 0, 0, 0);
    }
  }

  float atts[4], attd[4];
  #pragma unroll
  for (int cg = 0; cg < 4; ++cg) {
    atts[cg] = att_s[cg * 16 + fr];
    attd[cg] = att_d[cg * 16 + fr];
  }
  __syncthreads();
  unsigned short* ho = xb;

  #pragma unroll
  for (int j = 0; j < 4; ++j) {
    int nrel = wv * 16 + fq * 4 + j;
    float ps = acc[0][j]*atts[0] + acc[1][j]*atts[1]
             + acc[2][j]*atts[2] + acc[3][j]*atts[3];
    float pd = acc[0][j]*attd[0] + acc[1][j]*attd[1]
             + acc[2][j]*attd[2] + acc[3][j]*attd[3];
    #pragma unroll
    for (int mk = 1; mk < 16; mk <<= 1) {
      ps += __shfl_xor(ps, mk);
      pd += __shfl_xor(pd, mk);
    }
    if (fr == 0 && n0 + nrel < NN) { as_[n0 + nrel] = ps; ad_[n0 + nrel] = pd; }
    #pragma unroll
    for (int cg = 0; cg < 4; ++cg)
      ho[nrel * 72 + cg * 16 + fr] = f32_to_bf16u(acc[cg][j]);
  }
  __syncthreads();

  {
    int node = tid >> 2, ch = (tid & 3) << 4;
    if (n0 + node < NN) {
      ushort4 a0 = *(ushort4*)&ho[node * 72 + ch];
      ushort4 a1 = *(ushort4*)&ho[node * 72 + ch + 4];
      ushort4 a2 = *(ushort4*)&ho[node * 72 + ch + 8];
      ushort4 a3 = *(ushort4*)&ho[node * 72 + ch + 12];
      unsigned short* dst = &hb[(size_t)(n0 + node) * HD + ch];
      *(ushort4*)(dst) = a0;
      *(ushort4*)(dst + 4) = a1;
      *(ushort4*)(dst + 8) = a2;
      *(ushort4*)(dst + 12) = a3;
    }
  }
}

// Partition edges into fixed-capacity bucket regions, computing p per edge.
// LDS-ranked; ONE global cursor claim per (block,bucket). NBKT=1563:
// half the scatter targets / claims of the NPB=32 version.
__global__ __launch_bounds__(512) void k_part(const int* __restrict__ ei,
                                              const float* __restrict__ as_,
                                              const float* __restrict__ ad_,
                                              int* __restrict__ bktcur,
                                              int2* __restrict__ bktbuf,
                                              float* __restrict__ p_lin,
                                              int E, int M) {
  __shared__ int lcnt[NBKT];
  __shared__ int gbs[NBKT];
  const int tid = threadIdx.x;
  const int base = blockIdx.x * TILE;

  for (int c = tid; c < NBKT; c += 512) lcnt[c] = 0;
  __syncthreads();

  int pkx[NIT], rb[NIT];
  float tv[NIT];
  #pragma unroll
  for (int i = 0; i < NIT; ++i) {
    int m = base + i * 512 + tid;
    if (m < M) {
      int s, d;
      if (m < E) { s = ei[m]; d = ei[E + m]; }
      else       { s = m - E; d = s; }
      int b = d >> 6;
      pkx[i] = (s << 6) | (d & 63);          // s<2^17, fits 23 bits
      tv[i] = as_[s] + ad_[d];
      int r = atomicAdd(&lcnt[b], 1);        // r < TILE=4096 -> 12 bits
      rb[i] = (b << 12) | r;                 // b < 1563 -> 11 bits
    } else rb[i] = -1;
  }
  __syncthreads();

  for (int c = tid; c < NBKT; c += 512) {
    int v = lcnt[c];
    gbs[c] = v ? atomicAdd(&bktcur[c], v) : 0;
  }
  __syncthreads();

  #pragma unroll
  for (int i = 0; i < NIT; ++i) {
    if (rb[i] >= 0) {
      int m = base + i * 512 + tid;
      float t = tv[i];
      t = t > 0.f ? t : NEG * t;
      float p = __expf(t);
      p_lin[m] = p;
      int b = (unsigned)rb[i] >> 12, r = rb[i] & 4095;
      int slot = gbs[b] + r;
      if (slot < CAP)
        bktbuf[(size_t)b * CAP + slot] = make_int2(pkx[i], __float_as_int(p));
    }
  }
}

// One block per bucket of 64 nodes. Place by node in LDS, then the proven
// dword channel-pair gather (one VMEM = 2 edges, 8 edges in flight).
__global__ __launch_bounds__(256) void k_pg(const int* __restrict__ bktcur,
                                            const int2* __restrict__ bktbuf,
                                            const unsigned short* __restrict__ hb,
                                            const float* __restrict__ bias,
                                            float* __restrict__ out,
                                            float* __restrict__ denom) {
  __shared__ int2 sp[CAP];
  __shared__ int cnt2[NPB], nstart[NPB], cur[NPB];
  __shared__ float dls[NPB];
  const int b = blockIdx.x;
  const int d0 = b << 6;
  const int tid = threadIdx.x;
  const int cnt = min(bktcur[b], CAP);
  const int2* mybuf = bktbuf + (size_t)b * CAP;
  const char* hbb = (const char*)hb;

  if (tid < NPB) { cnt2[tid] = 0; dls[tid] = 0.f; }
  __syncthreads();
  for (int e = tid; e < cnt; e += 256) atomicAdd(&cnt2[mybuf[e].x & 63], 1);
  __syncthreads();

  if (tid < 64) {   // one wave exclusive-scans 64 counters
    int a = cnt2[tid];
    int va = a;
    #pragma unroll
    for (int off = 1; off < 64; off <<= 1) {
      int na = __shfl_up(va, off);
      if (tid >= off) va += na;
    }
    nstart[tid] = va - a;
    cur[tid] = va - a;
  }
  __syncthreads();
  for (int e = tid; e < cnt; e += 256) {
    int2 v = mybuf[e];
    int slot = atomicAdd(&cur[v.x & 63], 1);
    sp[slot] = make_int2((v.x & ~63) << 1, v.y);   // src*128 byte offset
  }
  __syncthreads();

  const int wv = tid >> 6, lane = tid & 63;
  const int half = lane >> 5;          // which edge of a pair
  const int hl = lane & 31;            // channel-pair index
  const unsigned chb = (unsigned)hl << 2;
  const float2 bs2 = *(const float2*)&bias[2 * hl];

  for (int n = wv; n < NPB; n += 4) {
    if (d0 + n >= NN) break;
    int beg = nstart[n], end = beg + cnt2[n];
    float ax = 0.f, ay = 0.f, dens = 0.f;
    int e = beg;
    for (; e + 8 <= end; e += 8) {        // 8 edges per iter, 4 loads in flight
      #pragma unroll
      for (int j = 0; j < 4; ++j) {
        int2 v = sp[e + 2 * j + half];
        unsigned u = *(const unsigned*)(hbb + ((unsigned)v.x + chb));
        float p = __int_as_float(v.y);
        dens += p;
        ax += p * __uint_as_float(u << 16);
        ay += p * __uint_as_float(u & 0xffff0000u);
      }
    }
    {                                      // guarded epilogue: 0-7 edges
      #pragma unroll
      for (int j = 0; j < 4; ++j) {
        int idx = e + 2 * j + half;
        if (idx < end) {
          int2 v = sp[idx];
          unsigned u = *(const unsigned*)(hbb + ((unsigned)v.x + chb));
          float p = __int_as_float(v.y);
          dens += p;
          ax += p * __uint_as_float(u << 16);
          ay += p * __uint_as_float(u & 0xffff0000u);
        }
      }
    }
    ax += __shfl_xor(ax, 32);
    ay += __shfl_xor(ay, 32);
    dens += __shfl_xor(dens, 32);
    if (half == 0) {
      float rd = 1.f / (dens + 1e-16f);
      float2 o;
      o.x = ax * rd + bs2.x;
      o.y = ay * rd + bs2.y;
      *(float2*)&out[(size_t)(d0 + n) * HD + 2 * hl] = o;
      if (hl == 0) dls[n] = dens;
    }
  }
  __syncthreads();
  if (tid < NPB && d0 + tid < NN) denom[d0 + tid] = dls[tid];  // coalesced
}

// alpha_out[m] = p_lin[m] / denom[dst]
__global__ __launch_bounds__(256) void k_alpha(const int* __restrict__ ei,
                                               const float* __restrict__ p_lin,
                                               const float* __restrict__ denom,
                                               float* __restrict__ alpha_out,
                                               int E, int M) {
  int m = blockIdx.x * 256 + threadIdx.x;
  if (m >= M) return;
  int d = (m < E) ? ei[E + m] : (m - E);
  alpha_out[m] = p_lin[m] / (denom[d] + 1e-16f);
}

extern "C" void kernel_launch(void* const* d_in, const int* in_sizes, int n_in,
                              void* d_out, int out_size, void* d_ws, size_t ws_size,
                              hipStream_t stream) {
  const float* x     = (const float*)d_in[0];
  const int*   ei    = (const int*)d_in[1];   // [2, E]: src row then dst row
  const float* W     = (const float*)d_in[2];
  const float* att_s = (const float*)d_in[3];
  const float* att_d = (const float*)d_in[4];
  const float* bias  = (const float*)d_in[5];

  const int E = in_sizes[1] / 2;
  const int M = E + NN;

  float* out       = (float*)d_out;              // [NN*HD]
  float* alpha_out = out + (size_t)NN * HD;      // [M]

  char* w = (char*)d_ws;
  auto alloc = [&](size_t bytes) {
    char* p = w;
    w += (bytes + 15) & ~(size_t)15;
    return p;
  };
  unsigned short* hb = (unsigned short*)alloc(sizeof(unsigned short) * (size_t)NN * HD);
  float* as_    = (float*)alloc(sizeof(float) * NN);
  float* ad_    = (float*)alloc(sizeof(float) * NN);
  float* denom  = (float*)alloc(sizeof(float) * NN);
  float* p_lin  = (float*)alloc(sizeof(float) * (size_t)M);
  int*   bktcur = (int*)alloc(sizeof(int) * NBKT);
  int2*  bktbuf = (int2*)alloc(sizeof(int2) * (size_t)NBKT * CAP);

  k_gemm<<<(NN + 63) / 64, 256, 0, stream>>>(x, W, att_s, att_d, hb, as_, ad_,
                                             bktcur);
  k_part<<<(M + TILE - 1) / TILE, 512, 0, stream>>>(ei, as_, ad_, bktcur,
                                                    bktbuf, p_lin, E, M);
  k_pg<<<NBKT, 256, 0, stream>>>(bktcur, bktbuf, hb, bias, out, denom);
  k_alpha<<<(M + 255) / 256, 256, 0, stream>>>(ei, p_lin, denom, alpha_out,
                                               E, M);
}